// Round 11
// baseline (836.255 us; speedup 1.0000x reference)
//
#include <hip/hip_runtime.h>
#include <hip/hip_bf16.h>
#include <stdint.h>

#define BATCH 4
#define SEQ   4096          // 64*64 spatial
#define CH    512
#define NGRP  32
#define GEPS  1e-6f

typedef short  short8  __attribute__((ext_vector_type(8)));
typedef float  floatx4 __attribute__((ext_vector_type(4)));
typedef long   longx2  __attribute__((ext_vector_type(2)));

static __device__ __forceinline__ short bf16b(float f) {
    __hip_bfloat16 h = __float2bfloat16(f);
    return __builtin_bit_cast(short, h);
}
static __device__ __forceinline__ float bf2f(short s) {
    unsigned u = ((unsigned)(unsigned short)s) << 16;
    return __builtin_bit_cast(float, u);
}
static __device__ __forceinline__ char fp8b(float f) {
    int pk = __builtin_amdgcn_cvt_pk_fp8_f32(f, f, 0, false);
    return (char)(pk & 0xff);
}

// async global->LDS, 16B per lane. LDS dest = wave-uniform base + lane*16.
static __device__ __forceinline__ void dma16(const void* g, void* l) {
    __builtin_amdgcn_global_load_lds(
        (const __attribute__((address_space(1))) unsigned int*)g,
        (__attribute__((address_space(3))) unsigned int*)l, 16, 0, 0);
}

// max-reduce across the 16 lanes of a DPP row, pure VALU
static __device__ __forceinline__ float rowmax16(float x) {
    int xi = __builtin_bit_cast(int, x);
    x = fmaxf(x, __builtin_bit_cast(float, __builtin_amdgcn_update_dpp(xi, xi, 0x128, 0xf, 0xf, true))); // row_ror:8
    xi = __builtin_bit_cast(int, x);
    x = fmaxf(x, __builtin_bit_cast(float, __builtin_amdgcn_update_dpp(xi, xi, 0x124, 0xf, 0xf, true))); // row_ror:4
    xi = __builtin_bit_cast(int, x);
    x = fmaxf(x, __builtin_bit_cast(float, __builtin_amdgcn_update_dpp(xi, xi, 0x122, 0xf, 0xf, true))); // row_ror:2
    xi = __builtin_bit_cast(int, x);
    x = fmaxf(x, __builtin_bit_cast(float, __builtin_amdgcn_update_dpp(xi, xi, 0x121, 0xf, 0xf, true))); // row_ror:1
    return x;
}

// ---------------- fused GroupNorm partial sums + weight transpose ----------------
__global__ __launch_bounds__(256) void gn_wt_kernel(const float* __restrict__ x,
                                                    float* __restrict__ statsraw,
                                                    const float* __restrict__ w0,
                                                    const float* __restrict__ w1,
                                                    const float* __restrict__ w2,
                                                    const float* __restrict__ w3,
                                                    short* __restrict__ wT) {
    __shared__ float a1[256], a2[256];
    __shared__ float trs[32][33];
    int blk = blockIdx.x;
    int t = threadIdx.x;
    if (blk < 256) {
        size_t row0 = (size_t)blk * 64;
        int qd = t & 127;
        int rh = t >> 7;
        const float* base = x + row0 * 512 + qd * 4;
        float s1 = 0.f, s2 = 0.f;
        #pragma unroll 4
        for (int i = 0; i < 32; ++i) {
            int r = rh + i * 2;
            float4 v = *reinterpret_cast<const float4*>(base + (size_t)r * 512);
            s1 += v.x + v.y + v.z + v.w;
            s2 += v.x * v.x + v.y * v.y + v.z * v.z + v.w * v.w;
        }
        a1[t] = s1; a2[t] = s2;
        __syncthreads();
        if (t < 32) {
            float u1 = 0.f, u2 = 0.f;
            #pragma unroll
            for (int e = 0; e < 4; ++e) {
                u1 += a1[t * 4 + e] + a1[128 + t * 4 + e];
                u2 += a2[t * 4 + e] + a2[128 + t * 4 + e];
            }
            int b = (int)(row0 >> 12);
            atomicAdd(&statsraw[(b * 32 + t) * 2],     u1);
            atomicAdd(&statsraw[(b * 32 + t) * 2 + 1], u2);
        }
    } else {
        int bz = (blk - 256) >> 8;
        int rem = (blk - 256) & 255;
        int n0 = (rem & 15) * 32, k0 = (rem >> 4) * 32;
        const float* w = (bz == 0) ? w0 : (bz == 1) ? w1 : (bz == 2) ? w2 : w3;
        short* out = wT + (size_t)bz * CH * CH;
        int tx = t & 31, ty = t >> 5;
        #pragma unroll
        for (int i = 0; i < 4; ++i) {
            int kk = ty + i * 8;
            trs[kk][tx] = w[(size_t)(k0 + kk) * CH + n0 + tx];
        }
        __syncthreads();
        #pragma unroll
        for (int i = 0; i < 4; ++i) {
            int nn = ty + i * 8;
            out[(size_t)(n0 + nn) * CH + k0 + tx] = bf16b(trs[tx][nn]);
        }
    }
}

// ---------------- GroupNorm apply ----------------
__global__ __launch_bounds__(256) void gn_apply_kernel(const float* __restrict__ x,
                                                       const float* __restrict__ statsraw,
                                                       const float* __restrict__ gsc,
                                                       const float* __restrict__ gbs,
                                                       short* __restrict__ xn) {
    int i4 = blockIdx.x * 256 + threadIdx.x;
    int base = i4 * 4;
    int b = base >> 21;
    int c = base & 511;
    int sidx = (b * 32 + (c >> 4)) * 2;
    float s1 = statsraw[sidx], s2 = statsraw[sidx + 1];
    float mean = s1 * (1.f / 65536.f);
    float var  = s2 * (1.f / 65536.f) - mean * mean;
    float rstd = rsqrtf(var + GEPS);
    float4 xv = reinterpret_cast<const float4*>(x)[i4];
    float4 sv = *reinterpret_cast<const float4*>(gsc + c);
    float4 bv = *reinterpret_cast<const float4*>(gbs + c);
    union { short s[4]; uint2 u; } p;
    p.s[0] = bf16b((xv.x - mean) * rstd * sv.x + bv.x);
    p.s[1] = bf16b((xv.y - mean) * rstd * sv.y + bv.y);
    p.s[2] = bf16b((xv.z - mean) * rstd * sv.z + bv.z);
    p.s[3] = bf16b((xv.w - mean) * rstd * sv.w + bv.w);
    reinterpret_cast<uint2*>(xn)[i4] = p.u;
}

// ---------------- fused QKV GEMM: fp8 epilogue (r8 version, unchanged) -------------
__global__ __launch_bounds__(256) void gemm_qkv_kernel(const short* __restrict__ A,
                                                       const short* __restrict__ wT,
                                                       const float* __restrict__ bq,
                                                       const float* __restrict__ bk,
                                                       const float* __restrict__ bv,
                                                       char* __restrict__ q8,
                                                       char* __restrict__ k8,
                                                       char* __restrict__ vT8) {
    __shared__ short As[128 * 64];
    __shared__ short Bs[128 * 64];
    __shared__ char  vls[128 * 144];   // fp8 store-staging, 18KB
    int m0 = blockIdx.x * 128;
    int nblk = blockIdx.y;                  // 0..11
    int which = nblk >> 2;                  // 0=q,1=k,2=v (block-uniform)
    int n0 = (nblk & 3) * 128;
    const short* BT = wT + (size_t)which * 512 * 512;
    const float* bias = (which == 0) ? bq : (which == 1) ? bk : bv;
    int t = threadIdx.x;
    int w = t >> 6, lane = t & 63;
    int wr = w >> 1, wc = w & 1;
    int l15 = lane & 15, l4 = lane >> 4;
    floatx4 acc[4][4];
    #pragma unroll
    for (int i = 0; i < 4; ++i)
        #pragma unroll
        for (int j = 0; j < 4; ++j) acc[i][j] = (floatx4){0.f, 0.f, 0.f, 0.f};

    for (int k0 = 0; k0 < 512; k0 += 64) {
        __syncthreads();
        #pragma unroll
        for (int i = 0; i < 4; ++i) {
            int c = i * 256 + t;
            int row = c >> 3, j = (c & 7) ^ (row & 7);
            dma16(&A[(size_t)(m0 + row) * 512 + k0 + j * 8], &As[(c & ~63) * 8]);
            dma16(&BT[(size_t)(n0 + row) * 512 + k0 + j * 8], &Bs[(c & ~63) * 8]);
        }
        __syncthreads();
        #pragma unroll
        for (int kk = 0; kk < 64; kk += 32) {
            short8 af[4], bf[4];
            #pragma unroll
            for (int i = 0; i < 4; ++i) {
                int row = wr * 64 + i * 16 + l15;
                int j = (kk >> 3) + l4;
                af[i] = *reinterpret_cast<const short8*>(&As[(row * 8 + (j ^ (l15 & 7))) * 8]);
            }
            #pragma unroll
            for (int j2 = 0; j2 < 4; ++j2) {
                int row = wc * 64 + j2 * 16 + l15;
                int j = (kk >> 3) + l4;
                bf[j2] = *reinterpret_cast<const short8*>(&Bs[(row * 8 + (j ^ (l15 & 7))) * 8]);
            }
            #pragma unroll
            for (int i = 0; i < 4; ++i)
                #pragma unroll
                for (int j2 = 0; j2 < 4; ++j2)
                    acc[i][j2] = __builtin_amdgcn_mfma_f32_16x16x32_bf16(af[i], bf[j2], acc[i][j2], 0, 0, 0);
        }
    }
    if (which == 0) {
        #pragma unroll
        for (int i = 0; i < 4; ++i)
            #pragma unroll
            for (int j = 0; j < 4; ++j)
                #pragma unroll
                for (int r = 0; r < 4; ++r) {
                    int rl = wr * 64 + i * 16 + l4 * 4 + r;
                    int cl = wc * 64 + j * 16 + l15;
                    vls[rl * 144 + cl] = fp8b(acc[i][j][r] + bias[n0 + cl]);
                }
        __syncthreads();
        #pragma unroll
        for (int p = 0; p < 4; ++p) {
            int slot = p * 256 + t;
            int c = slot >> 3, off = (slot & 7) * 16;
            uint4 v;
            __builtin_memcpy(&v, &vls[c * 144 + off], 16);
            *reinterpret_cast<uint4*>(&q8[(size_t)(m0 + c) * 512 + n0 + off]) = v;
        }
    } else if (which == 1) {
        #pragma unroll
        for (int i = 0; i < 4; ++i)
            #pragma unroll
            for (int j = 0; j < 4; ++j)
                #pragma unroll
                for (int r = 0; r < 4; ++r) {
                    int rl = wr * 64 + i * 16 + l4 * 4 + r;
                    int cl = wc * 64 + j * 16 + l15;
                    int sblk = rl >> 5, srow = rl & 15, hp = (rl >> 4) & 1;
                    int ch = (cl >> 3) ^ (srow & 7);
                    vls[sblk * 4096 + srow * 256 + ch * 16 + hp * 8 + (cl & 7)]
                        = fp8b(acc[i][j][r] + bias[n0 + cl]);
                }
        __syncthreads();
        int bb = m0 >> 12, sb0 = (m0 & 4095) >> 5;
        #pragma unroll
        for (int p = 0; p < 4; ++p) {
            int u = p * 256 + t;
            int sblk = u >> 8, srow = (u >> 4) & 15, ch = u & 15;
            uint4 v;
            __builtin_memcpy(&v, &vls[sblk * 4096 + srow * 256 + ((ch ^ (srow & 7)) * 16)], 16);
            char* dst = k8 + (size_t)bb * 2097152 + (size_t)(sb0 + sblk) * 16384
                      + srow * 1024 + n0 * 2 + ch * 16;
            *reinterpret_cast<uint4*>(dst) = v;
        }
    } else {
        __syncthreads();
        #pragma unroll
        for (int i = 0; i < 4; ++i)
            #pragma unroll
            for (int j = 0; j < 4; ++j)
                #pragma unroll
                for (int r = 0; r < 4; ++r) {
                    int rl = wr * 64 + i * 16 + l4 * 4 + r;     // local row (sequence)
                    int rp = (rl & ~31) | (((rl & 15) << 1) | ((rl >> 4) & 1));  // interleave
                    int cl = wc * 64 + j * 16 + l15;            // local col (d)
                    vls[cl * 144 + rp] = fp8b(acc[i][j][r] + bias[n0 + cl]);
                }
        __syncthreads();
        int b = m0 >> 12, l0 = m0 & 4095;
        #pragma unroll
        for (int p = 0; p < 4; ++p) {
            int slot = p * 256 + t;
            int c = slot >> 3, off = (slot & 7) * 16;   // off multiple of 16
            uint4 v;
            __builtin_memcpy(&v, &vls[c * 144 + off], 16);
            int dcol = n0 + c;
            int g = dcol >> 5, rr = dcol & 15, h = (dcol >> 4) & 1;
            int s = l0 + off;                    // interleaved s index, mult of 16
            int sb = s >> 5, mb = (s & 31) >> 3; // mb = 0 or 2
            char* dst = vT8 + (size_t)b * 2097152 + (size_t)sb * 16384
                      + (size_t)((((g * 16 + rr) * 4 + mb) * 16) + h * 8);
            unsigned long long lo = ((unsigned long long)v.y << 32) | v.x;
            unsigned long long hi = ((unsigned long long)v.w << 32) | v.z;
            *reinterpret_cast<unsigned long long*>(dst)      = lo;  // chunk mb
            *reinterpret_cast<unsigned long long*>(dst + 16) = hi;  // chunk mb+1
        }
    }
}

// ---------------- output GEMM with FUSED combine (merge coeffs hoisted) -------------
__global__ __launch_bounds__(256) void gemm_bt_kernel(const short* __restrict__ Opart,
                                                      const float* __restrict__ ml,
                                                      const short* __restrict__ BT,
                                                      const float* __restrict__ bias,
                                                      float* __restrict__ outf,
                                                      const float* __restrict__ resid) {
    __shared__ short As[128 * 64];
    __shared__ short Bs[128 * 64];
    int m0 = blockIdx.x * 128, n0 = blockIdx.y * 128;
    int t = threadIdx.x;
    int w = t >> 6, lane = t & 63;
    int wr = w >> 1, wc = w & 1;
    int l15 = lane & 15, l4 = lane >> 4;
    const size_t PART = (size_t)BATCH * SEQ;   // 16384 rows per part
    floatx4 acc[4][4];
    #pragma unroll
    for (int i = 0; i < 4; ++i)
        #pragma unroll
        for (int j = 0; j < 4; ++j) acc[i][j] = (floatx4){0.f, 0.f, 0.f, 0.f};

    float e0h[4], e1h[4];
    #pragma unroll
    for (int i = 0; i < 4; ++i) {
        int rl = (i * 256 + t) >> 3;
        size_t rowg = (size_t)(m0 + rl);
        float mA = ml[rowg * 2],          lA = ml[rowg * 2 + 1];
        float mB = ml[(PART + rowg) * 2], lB = ml[(PART + rowg) * 2 + 1];
        float mm = fmaxf(mA, mB);
        float e0 = exp2f(mA - mm), e1 = exp2f(mB - mm);
        float inv = 1.f / (e0 * lA + e1 * lB);
        e0h[i] = e0 * inv; e1h[i] = e1 * inv;
    }

    for (int k0 = 0; k0 < 512; k0 += 64) {
        __syncthreads();
        #pragma unroll
        for (int i = 0; i < 4; ++i) {
            int c = i * 256 + t;
            int rl = c >> 3, j = (c & 7) ^ (rl & 7);
            size_t rowg = (size_t)(m0 + rl);
            const short* s0 = Opart + rowg * 512 + k0 + j * 8;
            const short* s1 = s0 + PART * 512;
            uint4 a0 = *reinterpret_cast<const uint4*>(s0);
            uint4 a1 = *reinterpret_cast<const uint4*>(s1);
            union { uint4 u; short s[8]; } ua, ub, uo;
            ua.u = a0; ub.u = a1;
            #pragma unroll
            for (int e = 0; e < 8; ++e)
                uo.s[e] = bf16b(bf2f(ua.s[e]) * e0h[i] + bf2f(ub.s[e]) * e1h[i]);
            *reinterpret_cast<uint4*>(&As[c * 8]) = uo.u;    // ds_write_b128
            dma16(&BT[(size_t)(n0 + rl) * 512 + k0 + j * 8], &Bs[(c & ~63) * 8]);
        }
        __syncthreads();
        #pragma unroll
        for (int kk = 0; kk < 64; kk += 32) {
            short8 af[4], bf[4];
            #pragma unroll
            for (int i = 0; i < 4; ++i) {
                int row = wr * 64 + i * 16 + l15;
                int j = (kk >> 3) + l4;
                af[i] = *reinterpret_cast<const short8*>(&As[(row * 8 + (j ^ (l15 & 7))) * 8]);
            }
            #pragma unroll
            for (int j2 = 0; j2 < 4; ++j2) {
                int row = wc * 64 + j2 * 16 + l15;
                int j = (kk >> 3) + l4;
                bf[j2] = *reinterpret_cast<const short8*>(&Bs[(row * 8 + (j ^ (l15 & 7))) * 8]);
            }
            #pragma unroll
            for (int i = 0; i < 4; ++i)
                #pragma unroll
                for (int j2 = 0; j2 < 4; ++j2)
                    acc[i][j2] = __builtin_amdgcn_mfma_f32_16x16x32_bf16(af[i], bf[j2], acc[i][j2], 0, 0, 0);
        }
    }
    #pragma unroll
    for (int i = 0; i < 4; ++i)
        #pragma unroll
        for (int j = 0; j < 4; ++j)
            #pragma unroll
            for (int r = 0; r < 4; ++r) {
                int row = m0 + wr * 64 + i * 16 + l4 * 4 + r;
                int col = n0 + wc * 64 + j * 16 + l15;
                float vv = acc[i][j][r] + bias[col];
                outf[(size_t)row * 512 + col] = vv + resid[(size_t)row * 512 + col];
            }
}

// ---------------- flash attention: fp8, 4-wave x 32-q, shared K/V reads -------------
// r10 (64-col iters) + q-row doubling: 4 waves x 32 q-rows (2 groups of 16).
// Mechanism: K/V LDS reads are B-operands, independent of q-rows owned — so
// reading K/V ONCE per wave and feeding TWO q-groups halves LDS-read volume
// per unit work (512KB -> 256KB per CU-iter; LDS was the binding pipe).
// The j-loop and g-loops read each K/V b128 once, shared across both groups.
// 1 wave/SIMD (launch_bounds(256,1) -> 512-reg unified budget); est ~400 regs,
// under the ~450 no-spill line. Spill tripwire: WRITE_SIZE + VGPR_Count.
// All qg loops are #pragma unroll with literal bounds (no runtime reg indexing).
__global__ __launch_bounds__(256, 1) void flash_kernel(const char* __restrict__ q8,
                                                       const char* __restrict__ k8,
                                                       const char* __restrict__ v8,
                                                       short* __restrict__ Opart,
                                                       float* __restrict__ ml) {
    __shared__ __align__(16) char smem[141312];   // K dbuf 64K | V dbuf 64K | P 4x2560
    int bx = blockIdx.x;                 // 0..255
    int pb = bx & 7;                     // XCD-local (part,b)
    int part = pb >> 2, b = pb & 3;
    int q0 = (bx >> 3) * 128;            // 128 q rows per block
    int t = threadIdx.x, w = t >> 6, lane = t & 63;   // w = 0..3
    int l15 = lane & 15, l4 = lane >> 4;
    const float c2 = 0.06375873735f;     // (1/sqrt(512)) * log2(e)
    const float MARGIN = 7.2134752f;     // 5*log2(e); p <= 2^7.21 = 148 < 448

    // Q fp8 fragments: group qg rows = q0 + qg*64 + w*16 + l15
    long qf[2][16];
    #pragma unroll
    for (int qg = 0; qg < 2; ++qg) {
        const char* qrow = q8 + ((size_t)b * SEQ + q0 + qg * 64 + w * 16 + l15) * 512;
        #pragma unroll
        for (int ks = 0; ks < 16; ++ks)
            qf[qg][ks] = *reinterpret_cast<const long*>(qrow + ks * 32 + l4 * 8);
    }

    floatx4 acc[2][32];
    #pragma unroll
    for (int qg = 0; qg < 2; ++qg)
        #pragma unroll
        for (int i = 0; i < 32; ++i) acc[qg][i] = (floatx4){0.f, 0.f, 0.f, 0.f};
    floatx4 lacc[2];
    lacc[0] = (floatx4){0.f, 0.f, 0.f, 0.f};
    lacc[1] = (floatx4){0.f, 0.f, 0.f, 0.f};
    float mused[2][4] = {{-1e30f, -1e30f, -1e30f, -1e30f},
                         {-1e30f, -1e30f, -1e30f, -1e30f}};

    const long ones = 0x3838383838383838L;   // e4m3 1.0 x8

    const char* kbase = k8 + (size_t)b * SEQ * 512;
    const char* vbase = v8 + (size_t)b * 512 * SEQ;
    const int sb0 = part * 64;           // first 32-s block of this part

    const int ksw = l15 & 7;
    const int vsw = (l15 >> 1) & 3;
    // loop-invariant LDS read bases; per-iter offset = cur*32768, tile2 +16384
    const char* kA_E = smem + ((l15 * 64 + (l4 ^ ksw)) << 4);
    const char* kA_O = smem + ((l15 * 64 + ((4 + l4) ^ ksw)) << 4);
    const char* vA   = smem + 65536 + ((l15 * 4 + (l4 ^ vsw)) << 4);
    char* Ps = smem + 131072 + w * 2560;   // [qg*1280 + chunk*640]

    // precomputed per-thread DMA source byte-offsets (swizzle folded in).
    // 256 threads x 8 dma16 cover 2048 slots = two 16KB s-block tiles.
    int kSrc[8], vSrc[8];
    #pragma unroll
    for (int i = 0; i < 8; ++i) {
        int c = i * 256 + t;
        int tile = c >> 10, cw = c & 1023;
        kSrc[i] = tile * 16384 + (((cw & ~63) | ((cw & 63) ^ ((cw >> 6) & 7))) << 4);
        vSrc[i] = tile * 16384 + (((cw & ~3)  | ((cw & 3)  ^ ((cw >> 3) & 3))) << 4);
    }
    const int ldsD = (t & ~63) << 4;   // wave-uniform: w*1024

    // stage s-blocks sb, sb+1 into buffer `buf` (dest = linear slot*16)
    auto stage = [&](int sb, int buf) {
        const char* kt = kbase + (size_t)sb * 16384;
        const char* vt = vbase + (size_t)sb * 16384;
        char* Kd = smem + buf * 32768 + ldsD;
        char* Vd = smem + 65536 + buf * 32768 + ldsD;
        #pragma unroll
        for (int i = 0; i < 8; ++i) dma16(kt + kSrc[i], Kd + i * 4096);
        #pragma unroll
        for (int i = 0; i < 8; ++i) dma16(vt + vSrc[i], Vd + i * 4096);
    };

    stage(sb0, 0);
    __syncthreads();                                   // tiles 0,1 ready

    for (int it = 0; it < 32; ++it) {
        int cur = it & 1;
        int coff = cur << 15;
        if (it + 1 < 32) stage(sb0 + 2 * (it + 1), 1 - cur);

        // --- QK^T (fp8): K read ONCE per wave, shared by both q-groups.
        // s[qg][0..3] = tiles {blk0-lo, blk0-hi, blk1-lo, blk1-hi}
        floatx4 s0[4], s1[4];
        #pragma unroll
        for (int i = 0; i < 4; ++i) {
            s0[i] = (floatx4){0.f, 0.f, 0.f, 0.f};
            s1[i] = (floatx4){0.f, 0.f, 0.f, 0.f};
        }
        #pragma unroll
        for (int j = 0; j < 8; ++j) {
            longx2 kE0 = *reinterpret_cast<const longx2*>(kA_E + coff + j * 128);
            longx2 kO0 = *reinterpret_cast<const longx2*>(kA_O + coff + j * 128);
            longx2 kE1 = *reinterpret_cast<const longx2*>(kA_E + coff + 16384 + j * 128);
            longx2 kO1 = *reinterpret_cast<const longx2*>(kA_O + coff + 16384 + j * 128);
            s0[0] = __builtin_amdgcn_mfma_f32_16x16x32_fp8_fp8(qf[0][2 * j],     kE0[0], s0[0], 0, 0, 0);
            s0[1] = __builtin_amdgcn_mfma_f32_16x16x32_fp8_fp8(qf[0][2 * j],     kE0[1], s0[1], 0, 0, 0);
            s0[2] = __builtin_amdgcn_mfma_f32_16x16x32_fp8_fp8(qf[0][2 * j],     kE1[0], s0[2], 0, 0, 0);
            s0[3] = __builtin_amdgcn_mfma_f32_16x16x32_fp8_fp8(qf[0][2 * j],     kE1[1], s0[3], 0, 0, 0);
            s1[0] = __builtin_amdgcn_mfma_f32_16x16x32_fp8_fp8(qf[1][2 * j],     kE0[0], s1[0], 0, 0, 0);
            s1[1] = __builtin_amdgcn_mfma_f32_16x16x32_fp8_fp8(qf[1][2 * j],     kE0[1], s1[1], 0, 0, 0);
            s1[2] = __builtin_amdgcn_mfma_f32_16x16x32_fp8_fp8(qf[1][2 * j],     kE1[0], s1[2], 0, 0, 0);
            s1[3] = __builtin_amdgcn_mfma_f32_16x16x32_fp8_fp8(qf[1][2 * j],     kE1[1], s1[3], 0, 0, 0);
            s0[0] = __builtin_amdgcn_mfma_f32_16x16x32_fp8_fp8(qf[0][2 * j + 1], kO0[0], s0[0], 0, 0, 0);
            s0[1] = __builtin_amdgcn_mfma_f32_16x16x32_fp8_fp8(qf[0][2 * j + 1], kO0[1], s0[1], 0, 0, 0);
            s0[2] = __builtin_amdgcn_mfma_f32_16x16x32_fp8_fp8(qf[0][2 * j + 1], kO1[0], s0[2], 0, 0, 0);
            s0[3] = __builtin_amdgcn_mfma_f32_16x16x32_fp8_fp8(qf[0][2 * j + 1], kO1[1], s0[3], 0, 0, 0);
            s1[0] = __builtin_amdgcn_mfma_f32_16x16x32_fp8_fp8(qf[1][2 * j + 1], kO0[0], s1[0], 0, 0, 0);
            s1[1] = __builtin_amdgcn_mfma_f32_16x16x32_fp8_fp8(qf[1][2 * j + 1], kO0[1], s1[1], 0, 0, 0);
            s1[2] = __builtin_amdgcn_mfma_f32_16x16x32_fp8_fp8(qf[1][2 * j + 1], kO1[0], s1[2], 0, 0, 0);
            s1[3] = __builtin_amdgcn_mfma_f32_16x16x32_fp8_fp8(qf[1][2 * j + 1], kO1[1], s1[3], 0, 0, 0);
        }

        // --- online softmax per q-group, base-2, lazy rescale
        long pf[2][2];
        #pragma unroll
        for (int qg = 0; qg < 2; ++qg) {
            const floatx4* sq = (qg == 0) ? s0 : s1;   // qg literal -> folds
            float v00[4], v01[4], v10[4], v11[4], nm4[4];
            bool need = false;
            #pragma unroll
            for (int r = 0; r < 4; ++r) {
                v00[r] = sq[0][r] * c2; v01[r] = sq[1][r] * c2;
                v10[r] = sq[2][r] * c2; v11[r] = sq[3][r] * c2;
                nm4[r] = rowmax16(fmaxf(fmaxf(v00[r], v01[r]), fmaxf(v10[r], v11[r])));
                need |= (nm4[r] > mused[qg][r] + MARGIN);
            }
            if (__ballot(need)) {
                #pragma unroll
                for (int r = 0; r < 4; ++r) {
                    float nm = fmaxf(mused[qg][r], nm4[r]);
                    float al = exp2f(mused[qg][r] - nm);
                    lacc[qg][r] *= al;
                    #pragma unroll
                    for (int i = 0; i < 32; ++i) acc[qg][i][r] *= al;
                    mused[qg][r] = nm;
                }
            }
            char* Pq = Ps + qg * 1280;
            #pragma unroll
            for (int r = 0; r < 4; ++r) {
                int pk0 = __builtin_amdgcn_cvt_pk_fp8_f32(exp2f(v00[r] - mused[qg][r]),
                                                          exp2f(v01[r] - mused[qg][r]), 0, false);
                int pk1 = __builtin_amdgcn_cvt_pk_fp8_f32(exp2f(v10[r] - mused[qg][r]),
                                                          exp2f(v11[r] - mused[qg][r]), 0, false);
                *reinterpret_cast<short*>(Pq + (l4 * 4 + r) * 40 + l15 * 2)       = (short)pk0;
                *reinterpret_cast<short*>(Pq + 640 + (l4 * 4 + r) * 40 + l15 * 2) = (short)pk1;
            }
            __builtin_memcpy(&pf[qg][0], (const char*)__builtin_assume_aligned(Pq + l15 * 40 + l4 * 8, 8), 8);
            __builtin_memcpy(&pf[qg][1], (const char*)__builtin_assume_aligned(Pq + 640 + l15 * 40 + l4 * 8, 8), 8);
            lacc[qg] = __builtin_amdgcn_mfma_f32_16x16x32_fp8_fp8(pf[qg][0], ones, lacc[qg], 0, 0, 0);
            lacc[qg] = __builtin_amdgcn_mfma_f32_16x16x32_fp8_fp8(pf[qg][1], ones, lacc[qg], 0, 0, 0);
        }

        // --- PV: V read ONCE per wave, shared by both q-groups
        #pragma unroll
        for (int g = 0; g < 16; ++g) {
            longx2 va = *reinterpret_cast<const longx2*>(vA + coff + g * 1024);
            acc[0][2 * g]     = __builtin_amdgcn_mfma_f32_16x16x32_fp8_fp8(pf[0][0], va[0], acc[0][2 * g],     0, 0, 0);
            acc[0][2 * g + 1] = __builtin_amdgcn_mfma_f32_16x16x32_fp8_fp8(pf[0][0], va[1], acc[0][2 * g + 1], 0, 0, 0);
            acc[1][2 * g]     = __builtin_amdgcn_mfma_f32_16x16x32_fp8_fp8(pf[1][0], va[0], acc[1][2 * g],     0, 0, 0);
            acc[1][2 * g + 1] = __builtin_amdgcn_mfma_f32_16x16x32_fp8_fp8(pf[1][0], va[1], acc[1][2 * g + 1], 0, 0, 0);
        }
        #pragma unroll
        for (int g = 0; g < 16; ++g) {
            longx2 vb = *reinterpret_cast<const longx2*>(vA + coff + 16384 + g * 1024);
            acc[0][2 * g]     = __builtin_amdgcn_mfma_f32_16x16x32_fp8_fp8(pf[0][1], vb[0], acc[0][2 * g],     0, 0, 0);
            acc[0][2 * g + 1] = __builtin_amdgcn_mfma_f32_16x16x32_fp8_fp8(pf[0][1], vb[1], acc[0][2 * g + 1], 0, 0, 0);
            acc[1][2 * g]     = __builtin_amdgcn_mfma_f32_16x16x32_fp8_fp8(pf[1][1], vb[0], acc[1][2 * g],     0, 0, 0);
            acc[1][2 * g + 1] = __builtin_amdgcn_mfma_f32_16x16x32_fp8_fp8(pf[1][1], vb[1], acc[1][2 * g + 1], 0, 0, 0);
        }

        __syncthreads();    // drains DMA(it+1) + all reads of buf[cur] done
    }

    #pragma unroll
    for (int qg = 0; qg < 2; ++qg) {
        short* obase = Opart + (((size_t)part * BATCH + b) * SEQ + q0 + qg * 64 + w * 16) * 512;
        #pragma unroll
        for (int r = 0; r < 4; ++r) {
            #pragma unroll
            for (int tt = 0; tt < 32; ++tt)
                obase[(size_t)(l4 * 4 + r) * 512 + tt * 16 + l15] = bf16b(acc[qg][tt][r]);
        }
        if (l15 == 0) {
            #pragma unroll
            for (int r = 0; r < 4; ++r) {
                size_t rowg = ((size_t)part * BATCH + b) * SEQ + q0 + qg * 64 + w * 16 + l4 * 4 + r;
                ml[rowg * 2]     = mused[qg][r];      // base-2 units
                ml[rowg * 2 + 1] = lacc[qg][r];
            }
        }
    }
}

extern "C" void kernel_launch(void* const* d_in, const int* in_sizes, int n_in,
                              void* d_out, int out_size, void* d_ws, size_t ws_size,
                              hipStream_t stream) {
    const float* x   = (const float*)d_in[0];
    const float* gsc = (const float*)d_in[1];
    const float* gbs = (const float*)d_in[2];
    const float* wq  = (const float*)d_in[3];
    const float* bq  = (const float*)d_in[4];
    const float* wk  = (const float*)d_in[5];
    const float* bk  = (const float*)d_in[6];
    const float* wv  = (const float*)d_in[7];
    const float* bv  = (const float*)d_in[8];
    const float* wo  = (const float*)d_in[9];
    const float* bo  = (const float*)d_in[10];
    float* out = (float*)d_out;

    char* ws = (char*)d_ws;
    const size_t MB = 1ull << 20;
    short* xn    = (short*)ws;
    char*  q8    = (char*)(ws + 16 * MB);
    char*  k8    = (char*)(ws + 24 * MB);
    char*  vT8   = (char*)(ws + 32 * MB);
    short* Opart = (short*)(ws + 40 * MB);
    short* wT    = (short*)(ws + 72 * MB);
    float* stats = (float*)(ws + 74 * MB);
    float* ml    = (float*)(ws + 74 * MB + 65536);

    hipMemsetAsync(stats, 0, 256 * sizeof(float), stream);
    gn_wt_kernel<<<1280, 256, 0, stream>>>(x, stats, wq, wk, wv, wo, wT);
    gn_apply_kernel<<<8192, 256, 0, stream>>>(x, stats, gsc, gbs, xn);

    short* woT = wT + 786432;

    gemm_qkv_kernel<<<dim3(128, 12), 256, 0, stream>>>(xn, wT, bq, bk, bv, q8, k8, vT8);
    flash_kernel<<<256, 256, 0, stream>>>(q8, k8, vT8, Opart, ml);
    gemm_bt_kernel<<<dim3(128, 4), 256, 0, stream>>>(Opart, ml, woT, bo, out, x);
}